// Round 2
// baseline (983.347 us; speedup 1.0000x reference)
//
#include <hip/hip_runtime.h>
#include <hip/hip_bf16.h>

#define NR 8192
#define DIN 512
#define DD 256

typedef __attribute__((ext_vector_type(8))) short short8;
typedef __attribute__((ext_vector_type(4))) float f32x4;
typedef __attribute__((ext_vector_type(2))) unsigned long long u64x2;

static __device__ __forceinline__ unsigned short f2bf(float x) {
    __hip_bfloat16 b = __float2bfloat16(x);
    return __builtin_bit_cast(unsigned short, b);
}
static __device__ __forceinline__ float bf2f(unsigned short u) {
    unsigned v = ((unsigned)u) << 16;
    return __builtin_bit_cast(float, v);
}

// nibble -> 4 bf16 (0/1) via 16-entry LDS LUT; two lookups build a short8 frag.
// 16 distinct b64 addrs cover all 32 banks -> conflict-free (rest broadcast).
static __device__ __forceinline__ short8 frag_from_byte(
        const unsigned long long* __restrict__ lut, unsigned b) {
    u64x2 t;
    t.x = lut[b & 15u];
    t.y = lut[(b >> 4) & 15u];
    return __builtin_bit_cast(short8, t);
}

// ---------------------------------------------------------------------------
// K2: h = x @ W^T  (fp32-accurate via hi/lo bf16 split, 3 MFMA terms)
// grid (128, 2), block 256.  Tile 64 rows x 128 cols, BK=64.  (unchanged)
// ---------------------------------------------------------------------------
__global__ __launch_bounds__(256) void k_gemm_h(
        const float* __restrict__ x, const float* __restrict__ W,
        float* __restrict__ h) {
    __shared__ unsigned short Ah[64][72], Al[64][72];
    __shared__ unsigned short Bh[128][72], Bl[128][72];
    const int t = threadIdx.x;
    const int i0 = blockIdx.x * 64;
    const int n0 = blockIdx.y * 128;
    const int lane = t & 63, q = lane >> 4, lm = lane & 15;
    const int w = t >> 6, wm = w >> 1, wn = w & 1;
    const int ar = t >> 2, ac0 = (t & 3) << 4;
    const int bn = t >> 1, bh0 = (t & 1) << 5;
    f32x4 acc[2][4];
#pragma unroll
    for (int mt = 0; mt < 2; ++mt)
#pragma unroll
        for (int nt = 0; nt < 4; ++nt) acc[mt][nt] = (f32x4){0.f, 0.f, 0.f, 0.f};

    for (int kb = 0; kb < DIN; kb += 64) {
        __syncthreads();
        {
            const float4* xp = (const float4*)(x + (size_t)(i0 + ar) * DIN + kb + ac0);
#pragma unroll
            for (int u = 0; u < 4; ++u) {
                float4 v = xp[u];
                unsigned short h0 = f2bf(v.x), h1 = f2bf(v.y), h2 = f2bf(v.z), h3 = f2bf(v.w);
                unsigned short l0 = f2bf(v.x - bf2f(h0)), l1 = f2bf(v.y - bf2f(h1));
                unsigned short l2 = f2bf(v.z - bf2f(h2)), l3 = f2bf(v.w - bf2f(h3));
                *(uint2*)&Ah[ar][ac0 + u * 4] =
                    make_uint2((unsigned)h0 | ((unsigned)h1 << 16), (unsigned)h2 | ((unsigned)h3 << 16));
                *(uint2*)&Al[ar][ac0 + u * 4] =
                    make_uint2((unsigned)l0 | ((unsigned)l1 << 16), (unsigned)l2 | ((unsigned)l3 << 16));
            }
            const float4* wp = (const float4*)(W + (size_t)(n0 + bn) * DIN + kb + bh0);
#pragma unroll
            for (int u = 0; u < 8; ++u) {
                float4 v = wp[u];
                unsigned short h0 = f2bf(v.x), h1 = f2bf(v.y), h2 = f2bf(v.z), h3 = f2bf(v.w);
                unsigned short l0 = f2bf(v.x - bf2f(h0)), l1 = f2bf(v.y - bf2f(h1));
                unsigned short l2 = f2bf(v.z - bf2f(h2)), l3 = f2bf(v.w - bf2f(h3));
                *(uint2*)&Bh[bn][bh0 + u * 4] =
                    make_uint2((unsigned)h0 | ((unsigned)h1 << 16), (unsigned)h2 | ((unsigned)h3 << 16));
                *(uint2*)&Bl[bn][bh0 + u * 4] =
                    make_uint2((unsigned)l0 | ((unsigned)l1 << 16), (unsigned)l2 | ((unsigned)l3 << 16));
            }
        }
        __syncthreads();
#pragma unroll
        for (int ks = 0; ks < 64; ks += 32) {
            short8 fa_h[2], fa_l[2], fb_h[4], fb_l[4];
#pragma unroll
            for (int mt = 0; mt < 2; ++mt) {
                int r = wm * 32 + mt * 16 + lm;
                fa_h[mt] = *(const short8*)&Ah[r][ks + q * 8];
                fa_l[mt] = *(const short8*)&Al[r][ks + q * 8];
            }
#pragma unroll
            for (int nt = 0; nt < 4; ++nt) {
                int c = wn * 64 + nt * 16 + lm;
                fb_h[nt] = *(const short8*)&Bh[c][ks + q * 8];
                fb_l[nt] = *(const short8*)&Bl[c][ks + q * 8];
            }
#pragma unroll
            for (int mt = 0; mt < 2; ++mt)
#pragma unroll
                for (int nt = 0; nt < 4; ++nt) {
                    acc[mt][nt] = __builtin_amdgcn_mfma_f32_16x16x32_bf16(fa_h[mt], fb_h[nt], acc[mt][nt], 0, 0, 0);
                    acc[mt][nt] = __builtin_amdgcn_mfma_f32_16x16x32_bf16(fa_h[mt], fb_l[nt], acc[mt][nt], 0, 0, 0);
                    acc[mt][nt] = __builtin_amdgcn_mfma_f32_16x16x32_bf16(fa_l[mt], fb_h[nt], acc[mt][nt], 0, 0, 0);
                }
        }
    }
#pragma unroll
    for (int mt = 0; mt < 2; ++mt)
#pragma unroll
        for (int nt = 0; nt < 4; ++nt)
#pragma unroll
            for (int rr = 0; rr < 4; ++rr) {
                int row = i0 + wm * 32 + mt * 16 + q * 4 + rr;
                int col = n0 + wn * 64 + nt * 16 + lm;
                h[(size_t)row * DD + col] = acc[mt][nt][rr];
            }
}

// ---------------------------------------------------------------------------
// K3a: s_j = h[j,:] . a[256:512]; one wave per row; block partial max. (unchanged)
// ---------------------------------------------------------------------------
__global__ __launch_bounds__(256) void k_s(
        const float* __restrict__ h, const float* __restrict__ a,
        float* __restrict__ s, float* __restrict__ pmax) {
    __shared__ float wmax[4];
    const int t = threadIdx.x, w = t >> 6, lane = t & 63;
    const int row = blockIdx.x * 4 + w;
    float4 hv = *(const float4*)(h + (size_t)row * DD + lane * 4);
    float4 av = *(const float4*)(a + DD + lane * 4);
    float d = hv.x * av.x + hv.y * av.y + hv.z * av.z + hv.w * av.w;
#pragma unroll
    for (int off = 32; off; off >>= 1) d += __shfl_down(d, off);
    if (lane == 0) { s[row] = d; wmax[w] = d; }
    __syncthreads();
    if (t == 0)
        pmax[blockIdx.x] = fmaxf(fmaxf(wmax[0], wmax[1]), fmaxf(wmax[2], wmax[3]));
}

// ---------------------------------------------------------------------------
// K3b: global max of pmax[2048], then e_j = exp(s_j - M). (unchanged)
// ---------------------------------------------------------------------------
__global__ __launch_bounds__(1024) void k_e(
        const float* __restrict__ s, const float* __restrict__ pmax,
        float* __restrict__ e) {
    __shared__ float red[1024];
    const int t = threadIdx.x;
    red[t] = fmaxf(pmax[t], pmax[t + 1024]);
    __syncthreads();
    for (int off = 512; off; off >>= 1) {
        if (t < off) red[t] = fmaxf(red[t], red[t + off]);
        __syncthreads();
    }
    float M = red[0];
    for (int j = t; j < NR; j += 1024) e[j] = expf(s[j] - M);
}

// ---------------------------------------------------------------------------
// K4: g_t[d][j] = bf16(e_j * h[j][d])  (transposed, bf16) via LDS tile. (unchanged)
// ---------------------------------------------------------------------------
__global__ __launch_bounds__(256) void k_gt(
        const float* __restrict__ h, const float* __restrict__ e,
        unsigned short* __restrict__ gt) {
    __shared__ float tile[64][68];
    const int t = threadIdx.x;
    const int j0 = blockIdx.x * 64, d0 = blockIdx.y * 64;
    const int r = t >> 4, c4 = (t & 15) * 4;
#pragma unroll
    for (int rr = 0; rr < 4; ++rr) {
        int row = r + rr * 16;
        *(float4*)&tile[row][c4] = *(const float4*)(h + (size_t)(j0 + row) * DD + d0 + c4);
    }
    __syncthreads();
    float4 ev = *(const float4*)(e + j0 + c4);
#pragma unroll
    for (int rr = 0; rr < 4; ++rr) {
        int dd = r + rr * 16;
        unsigned short o0 = f2bf(ev.x * tile[c4 + 0][dd]);
        unsigned short o1 = f2bf(ev.y * tile[c4 + 1][dd]);
        unsigned short o2 = f2bf(ev.z * tile[c4 + 2][dd]);
        unsigned short o3 = f2bf(ev.w * tile[c4 + 3][dd]);
        *(uint2*)(gt + (size_t)(d0 + dd) * NR + j0 + c4) =
            make_uint2((unsigned)o0 | ((unsigned)o1 << 16), (unsigned)o2 | ((unsigned)o3 << 16));
    }
}

// ---------------------------------------------------------------------------
// K5 v2: 32 rows/block, grid 256 = 1 block/CU, block 1024 (16 waves).
// P1: stream adj ONCE (ballot -> 32 KB LDS bitmask, XOR-swizzled) + e-weighted
//     row denominators in the same pass.  BW-bound, barrier-free.
// P2: ZERO-BARRIER MFMA loop.  Waves = 4 col-groups x 4 K-groups (4x fewer
//     redundant A-frag LDS reads).  A-frags expanded from bitmask bytes via a
//     16-entry nibble->4xbf16 LUT (conflict-free b64).  B-frags straight from
//     gt (L2).  Alpha tiles written non-temporally INSIDE the loop (denoms
//     known after P1) so the 1 MB/CU of HBM writes overlaps gt reads + MFMA.
// P3: cross-K-group accumulator reduction in LDS (aliased over dead bitmask),
//     out0 = elu(num/denom).
// ---------------------------------------------------------------------------
__global__ __launch_bounds__(1024, 4) void k_fused(
        const int* __restrict__ adj, const unsigned short* __restrict__ gt,
        const float* __restrict__ e, float* __restrict__ out0,
        float* __restrict__ alpha) {
    __shared__ unsigned char bmred[49152];      // P1/P2: bitmask 32 KB; P3: red 48 KB
    __shared__ unsigned long long lut[16];      // nibble -> 4 bf16 (8 B)
    __shared__ float dnm_s[32];

    const int t = threadIdx.x;
    const int row0 = blockIdx.x * 32;
    const int lane = t & 63, w = t >> 6;

    if (t < 16) {
        unsigned long long v = 0;
        if (t & 1) v |= 0x3F80ull;
        if (t & 2) v |= 0x3F80ull << 16;
        if (t & 4) v |= 0x3F80ull << 32;
        if (t & 8) v |= 0x3F80ull << 48;
        lut[t] = v;
    }

    // ======================= P1: adj -> bitmask + denom =====================
    {
        const int r0 = w * 2, r1 = r0 + 1;
        const int* __restrict__ a0 = adj + (size_t)(row0 + r0) * NR;
        const int* __restrict__ a1 = adj + (size_t)(row0 + r1) * NR;
        const unsigned swz0 = (unsigned)((r0 & 7) << 4);
        const unsigned swz1 = (unsigned)((r1 & 7) << 4);
        float p0 = 0.f, p1 = 0.f;
#pragma unroll 4
        for (int itc = 0; itc < 128; ++itc) {
            const int col = itc * 64 + lane;
            int v0 = __builtin_nontemporal_load(a0 + col);
            int v1 = __builtin_nontemporal_load(a1 + col);
            float ec = e[col];
            unsigned long long b0 = __ballot(v0 != 0);
            unsigned long long b1 = __ballot(v1 != 0);
            p0 += v0 ? ec : 0.f;
            p1 += v1 ? ec : 0.f;
            if (lane == 0) {
                *(unsigned long long*)&bmred[(unsigned)(r0 * 1024 + itc * 8) ^ swz0] = b0;
                *(unsigned long long*)&bmred[(unsigned)(r1 * 1024 + itc * 8) ^ swz1] = b1;
            }
        }
#pragma unroll
        for (int off = 32; off; off >>= 1) {
            p0 += __shfl_down(p0, off);
            p1 += __shfl_down(p1, off);
        }
        if (lane == 0) { dnm_s[r0] = p0; dnm_s[r1] = p1; }
    }
    __syncthreads();
    if (t < 32) dnm_s[t] = 1.0f / dnm_s[t];
    __syncthreads();

    // ======================= P2: barrier-free MFMA + alpha ==================
    const int q = lane >> 4, lm = lane & 15;
    const int cg = w & 3, kg = w >> 2;            // 4 col-groups x 4 K-groups
    const int qs = q * 8;

    const unsigned short* __restrict__ gb0 = gt + (size_t)(cg * 64 + 0  + lm) * NR + kg * 2048 + q * 8;
    const unsigned short* __restrict__ gb1 = gt + (size_t)(cg * 64 + 16 + lm) * NR + kg * 2048 + q * 8;
    const unsigned short* __restrict__ gb2 = gt + (size_t)(cg * 64 + 32 + lm) * NR + kg * 2048 + q * 8;
    const unsigned short* __restrict__ gb3 = gt + (size_t)(cg * 64 + 48 + lm) * NR + kg * 2048 + q * 8;

    f32x4 acc[2][4];
#pragma unroll
    for (int mt = 0; mt < 2; ++mt)
#pragma unroll
        for (int nt = 0; nt < 4; ++nt) acc[mt][nt] = (f32x4){0.f, 0.f, 0.f, 0.f};

    // bitmask read addressing (A-frags): rows lm / 16+lm, 2-way after swizzle
    const unsigned bswz = (unsigned)((lm & 7) << 4);
    const int b0base = lm * 1024;
    const int b1base = (16 + lm) * 1024;

    // alpha slice addressing: this wave writes rows cg*8..cg*8+7,
    // cols kg*2048 + it*128 + (lane&7)*16 .. +15
    const int arow = cg * 8 + (lane >> 3);
    const int acol8 = lane & 7;
    const float invr_a = dnm_s[arow];
    float* __restrict__ aptr = alpha + (size_t)(row0 + arow) * NR + kg * 2048 + acol8 * 16;
    const unsigned aswz = (unsigned)((arow & 7) << 4);
    const int abase = arow * 1024;
    const int adw = (acol8 >> 1) * 4;
    const int ash = (acol8 & 1) * 16;

#pragma unroll 2
    for (int it = 0; it < 16; ++it) {
        const int kt = kg * 16 + it;
        const uint4 bm0 = *(const uint4*)&bmred[(unsigned)(b0base + kt * 16) ^ bswz];
        const uint4 bm1 = *(const uint4*)&bmred[(unsigned)(b1base + kt * 16) ^ bswz];
        const unsigned w0[4] = {bm0.x, bm0.y, bm0.z, bm0.w};
        const unsigned w1[4] = {bm1.x, bm1.y, bm1.z, bm1.w};
#pragma unroll
        for (int s = 0; s < 4; ++s) {
            const unsigned byte0 = (w0[s] >> qs) & 0xFFu;
            const unsigned byte1 = (w1[s] >> qs) & 0xFFu;
            short8 fa0 = frag_from_byte(lut, byte0);
            short8 fa1 = frag_from_byte(lut, byte1);
            const int ko = it * 128 + s * 32;
            short8 fb0 = *(const short8*)(gb0 + ko);
            short8 fb1 = *(const short8*)(gb1 + ko);
            short8 fb2 = *(const short8*)(gb2 + ko);
            short8 fb3 = *(const short8*)(gb3 + ko);
            acc[0][0] = __builtin_amdgcn_mfma_f32_16x16x32_bf16(fa0, fb0, acc[0][0], 0, 0, 0);
            acc[1][0] = __builtin_amdgcn_mfma_f32_16x16x32_bf16(fa1, fb0, acc[1][0], 0, 0, 0);
            acc[0][1] = __builtin_amdgcn_mfma_f32_16x16x32_bf16(fa0, fb1, acc[0][1], 0, 0, 0);
            acc[1][1] = __builtin_amdgcn_mfma_f32_16x16x32_bf16(fa1, fb1, acc[1][1], 0, 0, 0);
            acc[0][2] = __builtin_amdgcn_mfma_f32_16x16x32_bf16(fa0, fb2, acc[0][2], 0, 0, 0);
            acc[1][2] = __builtin_amdgcn_mfma_f32_16x16x32_bf16(fa1, fb2, acc[1][2], 0, 0, 0);
            acc[0][3] = __builtin_amdgcn_mfma_f32_16x16x32_bf16(fa0, fb3, acc[0][3], 0, 0, 0);
            acc[1][3] = __builtin_amdgcn_mfma_f32_16x16x32_bf16(fa1, fb3, acc[1][3], 0, 0, 0);
        }
        // ---- alpha tile for this kt (overlaps MFMA/gt via HBM write path) ----
        {
            const unsigned bwv =
                *(const unsigned*)&bmred[(unsigned)(abase + kt * 16 + adw) ^ aswz];
            const unsigned bits16 = (bwv >> ash) & 0xFFFFu;
            const float* __restrict__ epg = e + kt * 128 + acol8 * 16;
            float* __restrict__ apg = aptr + it * 128;
#pragma unroll
            for (int u = 0; u < 4; ++u) {
                float4 ev = *(const float4*)(epg + u * 4);
                f32x4 o;
                o.x = ((bits16 >> (u * 4 + 0)) & 1u) ? ev.x * invr_a : 0.f;
                o.y = ((bits16 >> (u * 4 + 1)) & 1u) ? ev.y * invr_a : 0.f;
                o.z = ((bits16 >> (u * 4 + 2)) & 1u) ? ev.z * invr_a : 0.f;
                o.w = ((bits16 >> (u * 4 + 3)) & 1u) ? ev.w * invr_a : 0.f;
                __builtin_nontemporal_store(o, (f32x4*)(apg + u * 4));
            }
        }
    }

    // ======================= P3: cross-kg reduction + out0 ==================
    __syncthreads();                 // bitmask dead; alias 48 KB float buffer
    float* red = (float*)bmred;
#pragma unroll
    for (int chunk = 0; chunk < 2; ++chunk) {      // chunk == mt (16 rows each)
        if (kg != 0) {
            const int base = (kg - 1) * 4096 + cg * 1024;
#pragma unroll
            for (int nt = 0; nt < 4; ++nt)
#pragma unroll
                for (int rr = 0; rr < 4; ++rr)
                    red[base + (q * 4 + rr) * 64 + nt * 16 + lm] = acc[chunk][nt][rr];
        }
        __syncthreads();
        if (kg == 0) {
#pragma unroll
            for (int nt = 0; nt < 4; ++nt)
#pragma unroll
                for (int rr = 0; rr < 4; ++rr) {
                    const int idx = cg * 1024 + (q * 4 + rr) * 64 + nt * 16 + lm;
                    float z = acc[chunk][nt][rr] + red[idx] + red[4096 + idx] + red[8192 + idx];
                    const int rrow = chunk * 16 + q * 4 + rr;
                    z *= dnm_s[rrow];
                    float oo = z > 0.f ? z : expm1f(z);
                    __builtin_nontemporal_store(oo,
                        &out0[(size_t)(row0 + rrow) * DD + cg * 64 + nt * 16 + lm]);
                }
        }
        __syncthreads();
    }
}

// ---------------------------------------------------------------------------
extern "C" void kernel_launch(void* const* d_in, const int* in_sizes, int n_in,
                              void* d_out, int out_size, void* d_ws, size_t ws_size,
                              hipStream_t stream) {
    const float* x = (const float*)d_in[0];
    const int* adj = (const int*)d_in[1];
    const float* W = (const float*)d_in[2];
    const float* a = (const float*)d_in[3];
    float* out0 = (float*)d_out;
    float* alpha = (float*)d_out + (size_t)NR * DD;

    char* ws = (char*)d_ws;
    float* h            = (float*)(ws + 0);          //  8,388,608 B
    float* s            = (float*)(ws + 8388608);    //     32,768 B
    float* pmax         = (float*)(ws + 8421376);    //      8,192 B
    float* e            = (float*)(ws + 8429568);    //     32,768 B
    unsigned short* gt  = (unsigned short*)(ws + 8462336);  // 4,194,304 B (end ~12.7 MB)

    k_gemm_h<<<dim3(128, 2), 256, 0, stream>>>(x, W, h);
    k_s<<<2048, 256, 0, stream>>>(h, a, s, pmax);
    k_e<<<1, 1024, 0, stream>>>(s, pmax, e);
    k_gt<<<dim3(128, 4), 256, 0, stream>>>(h, e, gt);
    k_fused<<<256, 1024, 0, stream>>>(adj, gt, e, out0, alpha);
}

// Round 3
// 633.042 us; speedup vs baseline: 1.5534x; 1.5534x over previous
//
#include <hip/hip_runtime.h>
#include <hip/hip_bf16.h>

#define NR 8192
#define DIN 512
#define DD 256

typedef __attribute__((ext_vector_type(8))) short short8;
typedef __attribute__((ext_vector_type(4))) float f32x4;
typedef __attribute__((ext_vector_type(2))) unsigned long long u64x2;

static __device__ __forceinline__ unsigned short f2bf(float x) {
    __hip_bfloat16 b = __float2bfloat16(x);
    return __builtin_bit_cast(unsigned short, b);
}
static __device__ __forceinline__ float bf2f(unsigned short u) {
    unsigned v = ((unsigned)u) << 16;
    return __builtin_bit_cast(float, v);
}

// nibble -> 4 bf16 (0/1) via 16-entry LDS LUT; two lookups build a short8 frag.
static __device__ __forceinline__ short8 frag_from_byte(
        const unsigned long long* __restrict__ lut, unsigned b) {
    u64x2 t;
    t.x = lut[b & 15u];
    t.y = lut[(b >> 4) & 15u];
    return __builtin_bit_cast(short8, t);
}

// ---------------------------------------------------------------------------
// K2: h = x @ W^T  (fp32-accurate via hi/lo bf16 split, 3 MFMA terms)
// grid (128, 2), block 256.  Tile 64 rows x 128 cols, BK=64.  (unchanged)
// ---------------------------------------------------------------------------
__global__ __launch_bounds__(256) void k_gemm_h(
        const float* __restrict__ x, const float* __restrict__ W,
        float* __restrict__ h) {
    __shared__ unsigned short Ah[64][72], Al[64][72];
    __shared__ unsigned short Bh[128][72], Bl[128][72];
    const int t = threadIdx.x;
    const int i0 = blockIdx.x * 64;
    const int n0 = blockIdx.y * 128;
    const int lane = t & 63, q = lane >> 4, lm = lane & 15;
    const int w = t >> 6, wm = w >> 1, wn = w & 1;
    const int ar = t >> 2, ac0 = (t & 3) << 4;
    const int bn = t >> 1, bh0 = (t & 1) << 5;
    f32x4 acc[2][4];
#pragma unroll
    for (int mt = 0; mt < 2; ++mt)
#pragma unroll
        for (int nt = 0; nt < 4; ++nt) acc[mt][nt] = (f32x4){0.f, 0.f, 0.f, 0.f};

    for (int kb = 0; kb < DIN; kb += 64) {
        __syncthreads();
        {
            const float4* xp = (const float4*)(x + (size_t)(i0 + ar) * DIN + kb + ac0);
#pragma unroll
            for (int u = 0; u < 4; ++u) {
                float4 v = xp[u];
                unsigned short h0 = f2bf(v.x), h1 = f2bf(v.y), h2 = f2bf(v.z), h3 = f2bf(v.w);
                unsigned short l0 = f2bf(v.x - bf2f(h0)), l1 = f2bf(v.y - bf2f(h1));
                unsigned short l2 = f2bf(v.z - bf2f(h2)), l3 = f2bf(v.w - bf2f(h3));
                *(uint2*)&Ah[ar][ac0 + u * 4] =
                    make_uint2((unsigned)h0 | ((unsigned)h1 << 16), (unsigned)h2 | ((unsigned)h3 << 16));
                *(uint2*)&Al[ar][ac0 + u * 4] =
                    make_uint2((unsigned)l0 | ((unsigned)l1 << 16), (unsigned)l2 | ((unsigned)l3 << 16));
            }
            const float4* wp = (const float4*)(W + (size_t)(n0 + bn) * DIN + kb + bh0);
#pragma unroll
            for (int u = 0; u < 8; ++u) {
                float4 v = wp[u];
                unsigned short h0 = f2bf(v.x), h1 = f2bf(v.y), h2 = f2bf(v.z), h3 = f2bf(v.w);
                unsigned short l0 = f2bf(v.x - bf2f(h0)), l1 = f2bf(v.y - bf2f(h1));
                unsigned short l2 = f2bf(v.z - bf2f(h2)), l3 = f2bf(v.w - bf2f(h3));
                *(uint2*)&Bh[bn][bh0 + u * 4] =
                    make_uint2((unsigned)h0 | ((unsigned)h1 << 16), (unsigned)h2 | ((unsigned)h3 << 16));
                *(uint2*)&Bl[bn][bh0 + u * 4] =
                    make_uint2((unsigned)l0 | ((unsigned)l1 << 16), (unsigned)l2 | ((unsigned)l3 << 16));
            }
        }
        __syncthreads();
#pragma unroll
        for (int ks = 0; ks < 64; ks += 32) {
            short8 fa_h[2], fa_l[2], fb_h[4], fb_l[4];
#pragma unroll
            for (int mt = 0; mt < 2; ++mt) {
                int r = wm * 32 + mt * 16 + lm;
                fa_h[mt] = *(const short8*)&Ah[r][ks + q * 8];
                fa_l[mt] = *(const short8*)&Al[r][ks + q * 8];
            }
#pragma unroll
            for (int nt = 0; nt < 4; ++nt) {
                int c = wn * 64 + nt * 16 + lm;
                fb_h[nt] = *(const short8*)&Bh[c][ks + q * 8];
                fb_l[nt] = *(const short8*)&Bl[c][ks + q * 8];
            }
#pragma unroll
            for (int mt = 0; mt < 2; ++mt)
#pragma unroll
                for (int nt = 0; nt < 4; ++nt) {
                    acc[mt][nt] = __builtin_amdgcn_mfma_f32_16x16x32_bf16(fa_h[mt], fb_h[nt], acc[mt][nt], 0, 0, 0);
                    acc[mt][nt] = __builtin_amdgcn_mfma_f32_16x16x32_bf16(fa_h[mt], fb_l[nt], acc[mt][nt], 0, 0, 0);
                    acc[mt][nt] = __builtin_amdgcn_mfma_f32_16x16x32_bf16(fa_l[mt], fb_h[nt], acc[mt][nt], 0, 0, 0);
                }
        }
    }
#pragma unroll
    for (int mt = 0; mt < 2; ++mt)
#pragma unroll
        for (int nt = 0; nt < 4; ++nt)
#pragma unroll
            for (int rr = 0; rr < 4; ++rr) {
                int row = i0 + wm * 32 + mt * 16 + q * 4 + rr;
                int col = n0 + wn * 64 + nt * 16 + lm;
                h[(size_t)row * DD + col] = acc[mt][nt][rr];
            }
}

// ---------------------------------------------------------------------------
// K3a: s_j = h[j,:] . a[256:512]; one wave per row; block partial max. (unchanged)
// ---------------------------------------------------------------------------
__global__ __launch_bounds__(256) void k_s(
        const float* __restrict__ h, const float* __restrict__ a,
        float* __restrict__ s, float* __restrict__ pmax) {
    __shared__ float wmax[4];
    const int t = threadIdx.x, w = t >> 6, lane = t & 63;
    const int row = blockIdx.x * 4 + w;
    float4 hv = *(const float4*)(h + (size_t)row * DD + lane * 4);
    float4 av = *(const float4*)(a + DD + lane * 4);
    float d = hv.x * av.x + hv.y * av.y + hv.z * av.z + hv.w * av.w;
#pragma unroll
    for (int off = 32; off; off >>= 1) d += __shfl_down(d, off);
    if (lane == 0) { s[row] = d; wmax[w] = d; }
    __syncthreads();
    if (t == 0)
        pmax[blockIdx.x] = fmaxf(fmaxf(wmax[0], wmax[1]), fmaxf(wmax[2], wmax[3]));
}

// ---------------------------------------------------------------------------
// K3b: global max of pmax[2048], then e_j = exp(s_j - M). (unchanged)
// ---------------------------------------------------------------------------
__global__ __launch_bounds__(1024) void k_e(
        const float* __restrict__ s, const float* __restrict__ pmax,
        float* __restrict__ e) {
    __shared__ float red[1024];
    const int t = threadIdx.x;
    red[t] = fmaxf(pmax[t], pmax[t + 1024]);
    __syncthreads();
    for (int off = 512; off; off >>= 1) {
        if (t < off) red[t] = fmaxf(red[t], red[t + off]);
        __syncthreads();
    }
    float M = red[0];
    for (int j = t; j < NR; j += 1024) e[j] = expf(s[j] - M);
}

// ---------------------------------------------------------------------------
// K4: g_t[d][j] = bf16(e_j * h[j][d])  (transposed, bf16) via LDS tile. (unchanged)
// ---------------------------------------------------------------------------
__global__ __launch_bounds__(256) void k_gt(
        const float* __restrict__ h, const float* __restrict__ e,
        unsigned short* __restrict__ gt) {
    __shared__ float tile[64][68];
    const int t = threadIdx.x;
    const int j0 = blockIdx.x * 64, d0 = blockIdx.y * 64;
    const int r = t >> 4, c4 = (t & 15) * 4;
#pragma unroll
    for (int rr = 0; rr < 4; ++rr) {
        int row = r + rr * 16;
        *(float4*)&tile[row][c4] = *(const float4*)(h + (size_t)(j0 + row) * DD + d0 + c4);
    }
    __syncthreads();
    float4 ev = *(const float4*)(e + j0 + c4);
#pragma unroll
    for (int rr = 0; rr < 4; ++rr) {
        int dd = r + rr * 16;
        unsigned short o0 = f2bf(ev.x * tile[c4 + 0][dd]);
        unsigned short o1 = f2bf(ev.y * tile[c4 + 1][dd]);
        unsigned short o2 = f2bf(ev.z * tile[c4 + 2][dd]);
        unsigned short o3 = f2bf(ev.w * tile[c4 + 3][dd]);
        *(uint2*)(gt + (size_t)(d0 + dd) * NR + j0 + c4) =
            make_uint2((unsigned)o0 | ((unsigned)o1 << 16), (unsigned)o2 | ((unsigned)o3 << 16));
    }
}

// ---------------------------------------------------------------------------
// K5 v3: 32 rows/block, grid 256 = 1 block/CU, block 1024 (16 waves).
// P1: adj streamed once -> LDS bitmask (ballot) + e-weighted denoms. (as R2)
// P2: pure load+MFMA loop, NO stores (R2's vmcnt in-order retirement made
//     in-loop HBM stores block L2 load waits).  Ping-pong register double
//     buffer: 8x b128 gt loads per half-iteration issued before consuming
//     the other buffer.  launch_bounds(1024) -> 128 VGPR budget.
// P3: cross-kg reduction in DEDICATED red LDS (no alias; bitmask stays live).
// P4: alpha replay, P1-style mapping: 64 lanes x 4 B contiguous = full
//     256-B lines per store instr (fixes R2's 2x write amplification),
//     bits from LDS bitmask, nt dword stores.
// ---------------------------------------------------------------------------
__global__ __launch_bounds__(1024) void k_fused(
        const int* __restrict__ adj, const unsigned short* __restrict__ gt,
        const float* __restrict__ e, float* __restrict__ out0,
        float* __restrict__ alpha) {
    __shared__ unsigned char bm[32768];         // bitmask, live P1..P4
    __shared__ float red[12288];                // P3 reduction (48 KB)
    __shared__ unsigned long long lut[16];      // nibble -> 4 bf16
    __shared__ float dnm_s[32];

    const int t = threadIdx.x;
    const int row0 = blockIdx.x * 32;
    const int lane = t & 63, w = t >> 6;

    if (t < 16) {
        unsigned long long v = 0;
        if (t & 1) v |= 0x3F80ull;
        if (t & 2) v |= 0x3F80ull << 16;
        if (t & 4) v |= 0x3F80ull << 32;
        if (t & 8) v |= 0x3F80ull << 48;
        lut[t] = v;
    }

    // ======================= P1: adj -> bitmask + denom =====================
    {
        const int r0 = w * 2, r1 = r0 + 1;
        const int* __restrict__ a0 = adj + (size_t)(row0 + r0) * NR;
        const int* __restrict__ a1 = adj + (size_t)(row0 + r1) * NR;
        const unsigned swz0 = (unsigned)((r0 & 7) << 4);
        const unsigned swz1 = (unsigned)((r1 & 7) << 4);
        float p0 = 0.f, p1 = 0.f;
#pragma unroll 4
        for (int itc = 0; itc < 128; ++itc) {
            const int col = itc * 64 + lane;
            int v0 = __builtin_nontemporal_load(a0 + col);
            int v1 = __builtin_nontemporal_load(a1 + col);
            float ec = e[col];
            unsigned long long b0 = __ballot(v0 != 0);
            unsigned long long b1 = __ballot(v1 != 0);
            p0 += v0 ? ec : 0.f;
            p1 += v1 ? ec : 0.f;
            if (lane == 0) {
                *(unsigned long long*)&bm[(unsigned)(r0 * 1024 + itc * 8) ^ swz0] = b0;
                *(unsigned long long*)&bm[(unsigned)(r1 * 1024 + itc * 8) ^ swz1] = b1;
            }
        }
#pragma unroll
        for (int off = 32; off; off >>= 1) {
            p0 += __shfl_down(p0, off);
            p1 += __shfl_down(p1, off);
        }
        if (lane == 0) { dnm_s[r0] = p0; dnm_s[r1] = p1; }
    }
    __syncthreads();
    if (t < 32) dnm_s[t] = 1.0f / dnm_s[t];
    __syncthreads();

    // ======================= P2: pure load+MFMA loop ========================
    const int q = lane >> 4, lm = lane & 15;
    const int cg = w & 3, kg = w >> 2;            // 4 col-groups x 4 K-groups
    const int qs = q * 8;

    const unsigned short* __restrict__ gb0 = gt + (size_t)(cg * 64 + 0  + lm) * NR + kg * 2048 + q * 8;
    const unsigned short* __restrict__ gb1 = gt + (size_t)(cg * 64 + 16 + lm) * NR + kg * 2048 + q * 8;
    const unsigned short* __restrict__ gb2 = gt + (size_t)(cg * 64 + 32 + lm) * NR + kg * 2048 + q * 8;
    const unsigned short* __restrict__ gb3 = gt + (size_t)(cg * 64 + 48 + lm) * NR + kg * 2048 + q * 8;

    f32x4 acc[2][4];
#pragma unroll
    for (int mt = 0; mt < 2; ++mt)
#pragma unroll
        for (int nt = 0; nt < 4; ++nt) acc[mt][nt] = (f32x4){0.f, 0.f, 0.f, 0.f};

    const unsigned bswz = (unsigned)((lm & 7) << 4);
    const int b0base = lm * 1024;
    const int b1base = (16 + lm) * 1024;

#define LOADH(B, KO) do {                                                      \
        B[0] = *(const short8*)(gb0 + (KO));                                   \
        B[1] = *(const short8*)(gb1 + (KO));                                   \
        B[2] = *(const short8*)(gb2 + (KO));                                   \
        B[3] = *(const short8*)(gb3 + (KO));                                   \
        B[4] = *(const short8*)(gb0 + (KO) + 32);                              \
        B[5] = *(const short8*)(gb1 + (KO) + 32);                              \
        B[6] = *(const short8*)(gb2 + (KO) + 32);                              \
        B[7] = *(const short8*)(gb3 + (KO) + 32);                              \
    } while (0)

#define HALF(B, WLO0, WLO1, WHI0, WHI1) do {                                   \
        short8 fa0 = frag_from_byte(lut, ((WLO0) >> qs) & 0xFFu);              \
        short8 fa1 = frag_from_byte(lut, ((WLO1) >> qs) & 0xFFu);              \
        acc[0][0] = __builtin_amdgcn_mfma_f32_16x16x32_bf16(fa0, B[0], acc[0][0], 0, 0, 0); \
        acc[1][0] = __builtin_amdgcn_mfma_f32_16x16x32_bf16(fa1, B[0], acc[1][0], 0, 0, 0); \
        acc[0][1] = __builtin_amdgcn_mfma_f32_16x16x32_bf16(fa0, B[1], acc[0][1], 0, 0, 0); \
        acc[1][1] = __builtin_amdgcn_mfma_f32_16x16x32_bf16(fa1, B[1], acc[1][1], 0, 0, 0); \
        acc[0][2] = __builtin_amdgcn_mfma_f32_16x16x32_bf16(fa0, B[2], acc[0][2], 0, 0, 0); \
        acc[1][2] = __builtin_amdgcn_mfma_f32_16x16x32_bf16(fa1, B[2], acc[1][2], 0, 0, 0); \
        acc[0][3] = __builtin_amdgcn_mfma_f32_16x16x32_bf16(fa0, B[3], acc[0][3], 0, 0, 0); \
        acc[1][3] = __builtin_amdgcn_mfma_f32_16x16x32_bf16(fa1, B[3], acc[1][3], 0, 0, 0); \
        short8 fb0 = frag_from_byte(lut, ((WHI0) >> qs) & 0xFFu);              \
        short8 fb1 = frag_from_byte(lut, ((WHI1) >> qs) & 0xFFu);              \
        acc[0][0] = __builtin_amdgcn_mfma_f32_16x16x32_bf16(fb0, B[4], acc[0][0], 0, 0, 0); \
        acc[1][0] = __builtin_amdgcn_mfma_f32_16x16x32_bf16(fb1, B[4], acc[1][0], 0, 0, 0); \
        acc[0][1] = __builtin_amdgcn_mfma_f32_16x16x32_bf16(fb0, B[5], acc[0][1], 0, 0, 0); \
        acc[1][1] = __builtin_amdgcn_mfma_f32_16x16x32_bf16(fb1, B[5], acc[1][1], 0, 0, 0); \
        acc[0][2] = __builtin_amdgcn_mfma_f32_16x16x32_bf16(fb0, B[6], acc[0][2], 0, 0, 0); \
        acc[1][2] = __builtin_amdgcn_mfma_f32_16x16x32_bf16(fb1, B[6], acc[1][2], 0, 0, 0); \
        acc[0][3] = __builtin_amdgcn_mfma_f32_16x16x32_bf16(fb0, B[7], acc[0][3], 0, 0, 0); \
        acc[1][3] = __builtin_amdgcn_mfma_f32_16x16x32_bf16(fb1, B[7], acc[1][3], 0, 0, 0); \
    } while (0)

    {
        short8 bufA[8], bufB[8];
        LOADH(bufA, 0);                            // prologue: it=0, half 0
        for (int it = 0; it < 16; ++it) {
            const int kt = kg * 16 + it;
            const uint4 m0 = *(const uint4*)&bm[(unsigned)(b0base + kt * 16) ^ bswz];
            const uint4 m1 = *(const uint4*)&bm[(unsigned)(b1base + kt * 16) ^ bswz];
            LOADH(bufB, it * 128 + 64);            // prefetch half 1
            HALF(bufA, m0.x, m1.x, m0.y, m1.y);    // consume half 0 (s=0,1)
            if (it < 15) LOADH(bufA, (it + 1) * 128);  // prefetch next half 0
            HALF(bufB, m0.z, m1.z, m0.w, m1.w);    // consume half 1 (s=2,3)
        }
    }
#undef LOADH
#undef HALF

    // ======================= P3: cross-kg reduction + out0 ==================
    __syncthreads();
#pragma unroll
    for (int chunk = 0; chunk < 2; ++chunk) {      // chunk == mt (16 rows each)
        if (kg != 0) {
            const int base = (kg - 1) * 4096 + cg * 1024;
#pragma unroll
            for (int nt = 0; nt < 4; ++nt)
#pragma unroll
                for (int rr = 0; rr < 4; ++rr)
                    red[base + (q * 4 + rr) * 64 + nt * 16 + lm] = acc[chunk][nt][rr];
        }
        __syncthreads();
        if (kg == 0) {
#pragma unroll
            for (int nt = 0; nt < 4; ++nt)
#pragma unroll
                for (int rr = 0; rr < 4; ++rr) {
                    const int idx = cg * 1024 + (q * 4 + rr) * 64 + nt * 16 + lm;
                    float z = acc[chunk][nt][rr] + red[idx] + red[4096 + idx] + red[8192 + idx];
                    const int rrow = chunk * 16 + q * 4 + rr;
                    z *= dnm_s[rrow];
                    float oo = z > 0.f ? z : expm1f(z);
                    __builtin_nontemporal_store(oo,
                        &out0[(size_t)(row0 + rrow) * DD + cg * 64 + nt * 16 + lm]);
                }
        }
        __syncthreads();
    }

    // ======================= P4: alpha replay (coalesced full lines) ========
    {
        const int r0 = w * 2, r1 = r0 + 1;
        const float inv0 = dnm_s[r0], inv1 = dnm_s[r1];
        const unsigned swz0 = (unsigned)((r0 & 7) << 4);
        const unsigned swz1 = (unsigned)((r1 & 7) << 4);
        float* __restrict__ o0 = alpha + (size_t)(row0 + r0) * NR;
        float* __restrict__ o1 = alpha + (size_t)(row0 + r1) * NR;
        const int bsh = lane & 7, bof = lane >> 3;
#pragma unroll 4
        for (int itc = 0; itc < 128; ++itc) {
            const int col = itc * 64 + lane;
            float ec = e[col];
            unsigned b0 = bm[(unsigned)(r0 * 1024 + itc * 8 + bof) ^ swz0];
            unsigned b1 = bm[(unsigned)(r1 * 1024 + itc * 8 + bof) ^ swz1];
            float v0 = ((b0 >> bsh) & 1u) ? ec * inv0 : 0.f;
            float v1 = ((b1 >> bsh) & 1u) ? ec * inv1 : 0.f;
            __builtin_nontemporal_store(v0, o0 + col);
            __builtin_nontemporal_store(v1, o1 + col);
        }
    }
}

// ---------------------------------------------------------------------------
extern "C" void kernel_launch(void* const* d_in, const int* in_sizes, int n_in,
                              void* d_out, int out_size, void* d_ws, size_t ws_size,
                              hipStream_t stream) {
    const float* x = (const float*)d_in[0];
    const int* adj = (const int*)d_in[1];
    const float* W = (const float*)d_in[2];
    const float* a = (const float*)d_in[3];
    float* out0 = (float*)d_out;
    float* alpha = (float*)d_out + (size_t)NR * DD;

    char* ws = (char*)d_ws;
    float* h            = (float*)(ws + 0);          //  8,388,608 B
    float* s            = (float*)(ws + 8388608);    //     32,768 B
    float* pmax         = (float*)(ws + 8421376);    //      8,192 B
    float* e            = (float*)(ws + 8429568);    //     32,768 B
    unsigned short* gt  = (unsigned short*)(ws + 8462336);  // 4,194,304 B (end ~12.7 MB)

    k_gemm_h<<<dim3(128, 2), 256, 0, stream>>>(x, W, h);
    k_s<<<2048, 256, 0, stream>>>(h, a, s, pmax);
    k_e<<<1, 1024, 0, stream>>>(s, pmax, e);
    k_gt<<<dim3(128, 4), 256, 0, stream>>>(h, e, gt);
    k_fused<<<256, 1024, 0, stream>>>(adj, gt, e, out0, alpha);
}

// Round 5
// 539.741 us; speedup vs baseline: 1.8219x; 1.1729x over previous
//
#include <hip/hip_runtime.h>
#include <hip/hip_bf16.h>

#define NR 8192
#define DIN 512
#define DD 256

typedef __attribute__((ext_vector_type(8))) short short8;
typedef __attribute__((ext_vector_type(4))) float f32x4;
typedef __attribute__((ext_vector_type(2))) unsigned long long u64x2;

static __device__ __forceinline__ unsigned short f2bf(float x) {
    __hip_bfloat16 b = __float2bfloat16(x);
    return __builtin_bit_cast(unsigned short, b);
}
static __device__ __forceinline__ float bf2f(unsigned short u) {
    unsigned v = ((unsigned)u) << 16;
    return __builtin_bit_cast(float, v);
}

// nibble -> 4 bf16 (0/1) via 16-entry LDS LUT; two lookups build a short8 frag.
static __device__ __forceinline__ short8 frag_from_byte(
        const unsigned long long* __restrict__ lut, unsigned b) {
    u64x2 t;
    t.x = lut[b & 15u];
    t.y = lut[(b >> 4) & 15u];
    return __builtin_bit_cast(short8, t);
}

// ---------------------------------------------------------------------------
// K2: h = x @ W^T  (fp32-accurate via hi/lo bf16 split, 3 MFMA terms)
// grid (128, 2), block 256.  Tile 64 rows x 128 cols, BK=64.  (unchanged)
// ---------------------------------------------------------------------------
__global__ __launch_bounds__(256) void k_gemm_h(
        const float* __restrict__ x, const float* __restrict__ W,
        float* __restrict__ h) {
    __shared__ unsigned short Ah[64][72], Al[64][72];
    __shared__ unsigned short Bh[128][72], Bl[128][72];
    const int t = threadIdx.x;
    const int i0 = blockIdx.x * 64;
    const int n0 = blockIdx.y * 128;
    const int lane = t & 63, q = lane >> 4, lm = lane & 15;
    const int w = t >> 6, wm = w >> 1, wn = w & 1;
    const int ar = t >> 2, ac0 = (t & 3) << 4;
    const int bn = t >> 1, bh0 = (t & 1) << 5;
    f32x4 acc[2][4];
#pragma unroll
    for (int mt = 0; mt < 2; ++mt)
#pragma unroll
        for (int nt = 0; nt < 4; ++nt) acc[mt][nt] = (f32x4){0.f, 0.f, 0.f, 0.f};

    for (int kb = 0; kb < DIN; kb += 64) {
        __syncthreads();
        {
            const float4* xp = (const float4*)(x + (size_t)(i0 + ar) * DIN + kb + ac0);
#pragma unroll
            for (int u = 0; u < 4; ++u) {
                float4 v = xp[u];
                unsigned short h0 = f2bf(v.x), h1 = f2bf(v.y), h2 = f2bf(v.z), h3 = f2bf(v.w);
                unsigned short l0 = f2bf(v.x - bf2f(h0)), l1 = f2bf(v.y - bf2f(h1));
                unsigned short l2 = f2bf(v.z - bf2f(h2)), l3 = f2bf(v.w - bf2f(h3));
                *(uint2*)&Ah[ar][ac0 + u * 4] =
                    make_uint2((unsigned)h0 | ((unsigned)h1 << 16), (unsigned)h2 | ((unsigned)h3 << 16));
                *(uint2*)&Al[ar][ac0 + u * 4] =
                    make_uint2((unsigned)l0 | ((unsigned)l1 << 16), (unsigned)l2 | ((unsigned)l3 << 16));
            }
            const float4* wp = (const float4*)(W + (size_t)(n0 + bn) * DIN + kb + bh0);
#pragma unroll
            for (int u = 0; u < 8; ++u) {
                float4 v = wp[u];
                unsigned short h0 = f2bf(v.x), h1 = f2bf(v.y), h2 = f2bf(v.z), h3 = f2bf(v.w);
                unsigned short l0 = f2bf(v.x - bf2f(h0)), l1 = f2bf(v.y - bf2f(h1));
                unsigned short l2 = f2bf(v.z - bf2f(h2)), l3 = f2bf(v.w - bf2f(h3));
                *(uint2*)&Bh[bn][bh0 + u * 4] =
                    make_uint2((unsigned)h0 | ((unsigned)h1 << 16), (unsigned)h2 | ((unsigned)h3 << 16));
                *(uint2*)&Bl[bn][bh0 + u * 4] =
                    make_uint2((unsigned)l0 | ((unsigned)l1 << 16), (unsigned)l2 | ((unsigned)l3 << 16));
            }
        }
        __syncthreads();
#pragma unroll
        for (int ks = 0; ks < 64; ks += 32) {
            short8 fa_h[2], fa_l[2], fb_h[4], fb_l[4];
#pragma unroll
            for (int mt = 0; mt < 2; ++mt) {
                int r = wm * 32 + mt * 16 + lm;
                fa_h[mt] = *(const short8*)&Ah[r][ks + q * 8];
                fa_l[mt] = *(const short8*)&Al[r][ks + q * 8];
            }
#pragma unroll
            for (int nt = 0; nt < 4; ++nt) {
                int c = wn * 64 + nt * 16 + lm;
                fb_h[nt] = *(const short8*)&Bh[c][ks + q * 8];
                fb_l[nt] = *(const short8*)&Bl[c][ks + q * 8];
            }
#pragma unroll
            for (int mt = 0; mt < 2; ++mt)
#pragma unroll
                for (int nt = 0; nt < 4; ++nt) {
                    acc[mt][nt] = __builtin_amdgcn_mfma_f32_16x16x32_bf16(fa_h[mt], fb_h[nt], acc[mt][nt], 0, 0, 0);
                    acc[mt][nt] = __builtin_amdgcn_mfma_f32_16x16x32_bf16(fa_h[mt], fb_l[nt], acc[mt][nt], 0, 0, 0);
                    acc[mt][nt] = __builtin_amdgcn_mfma_f32_16x16x32_bf16(fa_l[mt], fb_h[nt], acc[mt][nt], 0, 0, 0);
                }
        }
    }
#pragma unroll
    for (int mt = 0; mt < 2; ++mt)
#pragma unroll
        for (int nt = 0; nt < 4; ++nt)
#pragma unroll
            for (int rr = 0; rr < 4; ++rr) {
                int row = i0 + wm * 32 + mt * 16 + q * 4 + rr;
                int col = n0 + wn * 64 + nt * 16 + lm;
                h[(size_t)row * DD + col] = acc[mt][nt][rr];
            }
}

// ---------------------------------------------------------------------------
// K3a: s_j = h[j,:] . a[256:512]; one wave per row; block partial max. (unchanged)
// ---------------------------------------------------------------------------
__global__ __launch_bounds__(256) void k_s(
        const float* __restrict__ h, const float* __restrict__ a,
        float* __restrict__ s, float* __restrict__ pmax) {
    __shared__ float wmax[4];
    const int t = threadIdx.x, w = t >> 6, lane = t & 63;
    const int row = blockIdx.x * 4 + w;
    float4 hv = *(const float4*)(h + (size_t)row * DD + lane * 4);
    float4 av = *(const float4*)(a + DD + lane * 4);
    float d = hv.x * av.x + hv.y * av.y + hv.z * av.z + hv.w * av.w;
#pragma unroll
    for (int off = 32; off; off >>= 1) d += __shfl_down(d, off);
    if (lane == 0) { s[row] = d; wmax[w] = d; }
    __syncthreads();
    if (t == 0)
        pmax[blockIdx.x] = fmaxf(fmaxf(wmax[0], wmax[1]), fmaxf(wmax[2], wmax[3]));
}

// ---------------------------------------------------------------------------
// K3b: global max of pmax[2048], then e_j = exp(s_j - M). (unchanged)
// ---------------------------------------------------------------------------
__global__ __launch_bounds__(1024) void k_e(
        const float* __restrict__ s, const float* __restrict__ pmax,
        float* __restrict__ e) {
    __shared__ float red[1024];
    const int t = threadIdx.x;
    red[t] = fmaxf(pmax[t], pmax[t + 1024]);
    __syncthreads();
    for (int off = 512; off; off >>= 1) {
        if (t < off) red[t] = fmaxf(red[t], red[t + off]);
        __syncthreads();
    }
    float M = red[0];
    for (int j = t; j < NR; j += 1024) e[j] = expf(s[j] - M);
}

// ---------------------------------------------------------------------------
// K4: g_t[d][j] = bf16(e_j * h[j][d])  (transposed, bf16) via LDS tile. (unchanged)
// ---------------------------------------------------------------------------
__global__ __launch_bounds__(256) void k_gt(
        const float* __restrict__ h, const float* __restrict__ e,
        unsigned short* __restrict__ gt) {
    __shared__ float tile[64][68];
    const int t = threadIdx.x;
    const int j0 = blockIdx.x * 64, d0 = blockIdx.y * 64;
    const int r = t >> 4, c4 = (t & 15) * 4;
#pragma unroll
    for (int rr = 0; rr < 4; ++rr) {
        int row = r + rr * 16;
        *(float4*)&tile[row][c4] = *(const float4*)(h + (size_t)(j0 + row) * DD + d0 + c4);
    }
    __syncthreads();
    float4 ev = *(const float4*)(e + j0 + c4);
#pragma unroll
    for (int rr = 0; rr < 4; ++rr) {
        int dd = r + rr * 16;
        unsigned short o0 = f2bf(ev.x * tile[c4 + 0][dd]);
        unsigned short o1 = f2bf(ev.y * tile[c4 + 1][dd]);
        unsigned short o2 = f2bf(ev.z * tile[c4 + 2][dd]);
        unsigned short o3 = f2bf(ev.w * tile[c4 + 3][dd]);
        *(uint2*)(gt + (size_t)(d0 + dd) * NR + j0 + c4) =
            make_uint2((unsigned)o0 | ((unsigned)o1 << 16), (unsigned)o2 | ((unsigned)o3 << 16));
    }
}

// ---------------------------------------------------------------------------
// K5 v4 (resubmit — R4 bench was an infra failure, same signature as R0):
// producer/consumer wave specialization.  32 rows/block, grid 256,
// block 1024 (16 waves), one __syncthreads total.
//   producers (waves 0-7, 4 adj-rows each): stream adj -> ballot bitmask into
//     LDS in 16 column-chunks (release-atomic flag per chunk) + e-weighted
//     denominators; then write their alpha rows (nt, full 256-B lines).
//   consumers (waves 8-15, 32 out-cols each, FULL K): spin (acquire+s_sleep)
//     on chunk flags; gt b128 loads ping-pong prefetched (gt never waits on
//     flags, only bitmask reads do); 16 MFMA per kt; no cross-wave reduction.
// HBM-read (adj), L2-read+MFMA (gt), HBM-write (alpha) run CONCURRENTLY.
// Deadlock-free: producers never wait; consumers wait on monotone counters;
// all 16 waves co-resident (single workgroup).
// ---------------------------------------------------------------------------
__global__ __launch_bounds__(1024) void k_fused(
        const int* __restrict__ adj, const unsigned short* __restrict__ gt,
        const float* __restrict__ e, float* __restrict__ out0,
        float* __restrict__ alpha) {
    __shared__ __attribute__((aligned(16))) unsigned char bm[32768];
    __shared__ unsigned long long lut[16];
    __shared__ float dnm_s[32];            // stores INVERSE denominators
    __shared__ int chunk_cnt[16];
    __shared__ int dnm_ready;

    const int t = threadIdx.x;
    const int row0 = blockIdx.x * 32;
    const int lane = t & 63, w = t >> 6;

    if (t < 16) {
        unsigned long long v = 0;
        if (t & 1) v |= 0x3F80ull;
        if (t & 2) v |= 0x3F80ull << 16;
        if (t & 4) v |= 0x3F80ull << 32;
        if (t & 8) v |= 0x3F80ull << 48;
        lut[t] = v;
        chunk_cnt[t] = 0;
    }
    if (t == 16) dnm_ready = 0;
    __syncthreads();                       // the only block-wide barrier

    if (w < 8) {
        // ========================= PRODUCER =================================
        const int r0 = w * 4;
        const int* __restrict__ ap0 = adj + (size_t)(row0 + r0) * NR;
        float ds0 = 0.f, ds1 = 0.f, ds2 = 0.f, ds3 = 0.f;

        for (int ch = 0; ch < 16; ++ch) {
#pragma unroll
            for (int g = 0; g < 2; ++g) {
                const int itc0 = ch * 8 + g * 4;
                int v[4][4];
                float ec[4];
#pragma unroll
                for (int u = 0; u < 4; ++u) ec[u] = e[(itc0 + u) * 64 + lane];
#pragma unroll
                for (int rr = 0; rr < 4; ++rr)
#pragma unroll
                    for (int u = 0; u < 4; ++u)
                        v[rr][u] = __builtin_nontemporal_load(
                            ap0 + (size_t)rr * NR + (itc0 + u) * 64 + lane);
#pragma unroll
                for (int u = 0; u < 4; ++u) {
                    unsigned long long b0 = __ballot(v[0][u] != 0);
                    unsigned long long b1 = __ballot(v[1][u] != 0);
                    unsigned long long b2 = __ballot(v[2][u] != 0);
                    unsigned long long b3 = __ballot(v[3][u] != 0);
                    ds0 += v[0][u] ? ec[u] : 0.f;
                    ds1 += v[1][u] ? ec[u] : 0.f;
                    ds2 += v[2][u] ? ec[u] : 0.f;
                    ds3 += v[3][u] ? ec[u] : 0.f;
                    if (lane < 4) {
                        unsigned long long bv = lane == 0 ? b0 :
                                                lane == 1 ? b1 :
                                                lane == 2 ? b2 : b3;
                        const int r = r0 + lane;
                        *(unsigned long long*)&bm[
                            (unsigned)(r * 1024 + (itc0 + u) * 8) ^
                            ((unsigned)(r & 7) << 4)] = bv;
                    }
                }
            }
            if (lane == 0)
                __hip_atomic_fetch_add(&chunk_cnt[ch], 1, __ATOMIC_RELEASE,
                                       __HIP_MEMORY_SCOPE_WORKGROUP);
        }
        // ---- denominators (all lanes get the sums via butterfly) ----
#pragma unroll
        for (int off = 32; off; off >>= 1) {
            ds0 += __shfl_xor(ds0, off);
            ds1 += __shfl_xor(ds1, off);
            ds2 += __shfl_xor(ds2, off);
            ds3 += __shfl_xor(ds3, off);
        }
        const float inv0 = 1.f / ds0, inv1 = 1.f / ds1;
        const float inv2 = 1.f / ds2, inv3 = 1.f / ds3;
        if (lane == 0) {
            dnm_s[r0 + 0] = inv0;
            dnm_s[r0 + 1] = inv1;
            dnm_s[r0 + 2] = inv2;
            dnm_s[r0 + 3] = inv3;
        }
        if (lane == 0)
            __hip_atomic_fetch_add(&dnm_ready, 1, __ATOMIC_RELEASE,
                                   __HIP_MEMORY_SCOPE_WORKGROUP);

        // ---- alpha replay for own 4 rows (full-line nt stores) ----
        float* __restrict__ al0 = alpha + (size_t)(row0 + r0) * NR;
        const int bof = lane >> 3, bsh = lane & 7;
#pragma unroll 2
        for (int itc = 0; itc < 128; ++itc) {
            const int col = itc * 64 + lane;
            const float ec = e[col];
#pragma unroll
            for (int rr = 0; rr < 4; ++rr) {
                const int r = r0 + rr;
                unsigned byte = bm[(unsigned)(r * 1024 + itc * 8 + bof) ^
                                   ((unsigned)(r & 7) << 4)];
                const float inv = rr == 0 ? inv0 : rr == 1 ? inv1 :
                                  rr == 2 ? inv2 : inv3;
                float val = ((byte >> bsh) & 1u) ? ec * inv : 0.f;
                __builtin_nontemporal_store(val, al0 + (size_t)rr * NR + col);
            }
        }
    } else {
        // ========================= CONSUMER =================================
        const int cw = w - 8;                   // 0..7: 32 cols each
        const int q = lane >> 4, lm = lane & 15;
        const int qs = q * 8;
        const unsigned bswz = (unsigned)((lm & 7) << 4);
        const int b0base = lm * 1024;
        const int b1base = (16 + lm) * 1024;

        const unsigned short* __restrict__ gb0 =
            gt + (size_t)(cw * 32 + lm) * NR + q * 8;
        const unsigned short* __restrict__ gb1 =
            gt + (size_t)(cw * 32 + 16 + lm) * NR + q * 8;

        f32x4 acc[2][2];
#pragma unroll
        for (int mt = 0; mt < 2; ++mt)
#pragma unroll
            for (int nt = 0; nt < 2; ++nt) acc[mt][nt] = (f32x4){0.f, 0.f, 0.f, 0.f};

#define LOADK(B, KO) do {                                                      \
        B[0] = *(const short8*)(gb0 + (KO));                                   \
        B[1] = *(const short8*)(gb0 + (KO) + 32);                              \
        B[2] = *(const short8*)(gb0 + (KO) + 64);                              \
        B[3] = *(const short8*)(gb0 + (KO) + 96);                              \
        B[4] = *(const short8*)(gb1 + (KO));                                   \
        B[5] = *(const short8*)(gb1 + (KO) + 32);                              \
        B[6] = *(const short8*)(gb1 + (KO) + 64);                              \
        B[7] = *(const short8*)(gb1 + (KO) + 96);                              \
    } while (0)

#define SSTEP(B, S, W0, W1) do {                                               \
        short8 fa0 = frag_from_byte(lut, ((W0) >> qs) & 0xFFu);                \
        short8 fa1 = frag_from_byte(lut, ((W1) >> qs) & 0xFFu);                \
        acc[0][0] = __builtin_amdgcn_mfma_f32_16x16x32_bf16(fa0, B[S], acc[0][0], 0, 0, 0);     \
        acc[1][0] = __builtin_amdgcn_mfma_f32_16x16x32_bf16(fa1, B[S], acc[1][0], 0, 0, 0);     \
        acc[0][1] = __builtin_amdgcn_mfma_f32_16x16x32_bf16(fa0, B[4 + S], acc[0][1], 0, 0, 0); \
        acc[1][1] = __builtin_amdgcn_mfma_f32_16x16x32_bf16(fa1, B[4 + S], acc[1][1], 0, 0, 0); \
    } while (0)

#define CSTEP(B, M0, M1) do {                                                  \
        SSTEP(B, 0, (M0).x, (M1).x);                                           \
        SSTEP(B, 1, (M0).y, (M1).y);                                           \
        SSTEP(B, 2, (M0).z, (M1).z);                                           \
        SSTEP(B, 3, (M0).w, (M1).w);                                           \
    } while (0)

        short8 bA[8], bB[8];
        LOADK(bA, 0);                          // gt prefetch needs no flag
        for (int ch = 0; ch < 16; ++ch) {
            while (__hip_atomic_load(&chunk_cnt[ch], __ATOMIC_ACQUIRE,
                                     __HIP_MEMORY_SCOPE_WORKGROUP) < 8)
                __builtin_amdgcn_s_sleep(1);
            const int kt0 = ch * 4;
#pragma unroll
            for (int k2 = 0; k2 < 4; k2 += 2) {
                const int kt = kt0 + k2;
                uint4 m0a = *(const uint4*)&bm[(unsigned)(b0base + kt * 16) ^ bswz];
                uint4 m1a = *(const uint4*)&bm[(unsigned)(b1base + kt * 16) ^ bswz];
                LOADK(bB, (kt + 1) * 128);
                CSTEP(bA, m0a, m1a);
                uint4 m0b = *(const uint4*)&bm[(unsigned)(b0base + (kt + 1) * 16) ^ bswz];
                uint4 m1b = *(const uint4*)&bm[(unsigned)(b1base + (kt + 1) * 16) ^ bswz];
                if (kt + 2 < 64) LOADK(bA, (kt + 2) * 128);
                CSTEP(bB, m0b, m1b);
            }
        }
#undef LOADK
#undef SSTEP
#undef CSTEP

        // ---- out0 = elu(num * inv) ----
        while (__hip_atomic_load(&dnm_ready, __ATOMIC_ACQUIRE,
                                 __HIP_MEMORY_SCOPE_WORKGROUP) < 8)
            __builtin_amdgcn_s_sleep(1);
#pragma unroll
        for (int mt = 0; mt < 2; ++mt)
#pragma unroll
            for (int nt = 0; nt < 2; ++nt)
#pragma unroll
                for (int rr = 0; rr < 4; ++rr) {
                    const int rrow = mt * 16 + q * 4 + rr;
                    float z = acc[mt][nt][rr] * dnm_s[rrow];
                    float oo = z > 0.f ? z : expm1f(z);
                    __builtin_nontemporal_store(oo,
                        &out0[(size_t)(row0 + rrow) * DD + cw * 32 + nt * 16 + lm]);
                }
    }
}

// ---------------------------------------------------------------------------
extern "C" void kernel_launch(void* const* d_in, const int* in_sizes, int n_in,
                              void* d_out, int out_size, void* d_ws, size_t ws_size,
                              hipStream_t stream) {
    const float* x = (const float*)d_in[0];
    const int* adj = (const int*)d_in[1];
    const float* W = (const float*)d_in[2];
    const float* a = (const float*)d_in[3];
    float* out0 = (float*)d_out;
    float* alpha = (float*)d_out + (size_t)NR * DD;

    char* ws = (char*)d_ws;
    float* h            = (float*)(ws + 0);          //  8,388,608 B
    float* s            = (float*)(ws + 8388608);    //     32,768 B
    float* pmax         = (float*)(ws + 8421376);    //      8,192 B
    float* e            = (float*)(ws + 8429568);    //     32,768 B
    unsigned short* gt  = (unsigned short*)(ws + 8462336);  // 4,194,304 B (end ~12.7 MB)

    k_gemm_h<<<dim3(128, 2), 256, 0, stream>>>(x, W, h);
    k_s<<<2048, 256, 0, stream>>>(h, a, s, pmax);
    k_e<<<1, 1024, 0, stream>>>(s, pmax, e);
    k_gt<<<dim3(128, 4), 256, 0, stream>>>(h, e, gt);
    k_fused<<<256, 1024, 0, stream>>>(adj, gt, e, out0, alpha);
}